// Round 11
// baseline (294.334 us; speedup 1.0000x reference)
//
#include <hip/hip_runtime.h>
#include <hip/hip_cooperative_groups.h>
#include <math.h>

namespace cg = cooperative_groups;

#define N 16384
#define NWORDS 256       // N/64
#define FEAT 512
#define NUM_CATS 65
#define K 25
#define MAX_DETS 1000

// ---------------- ws layout (bytes) ----------------
// ckeys    : u64[N]            @ 0         (131072)  compacted candidate keys
// rank     : u32[N]            @ 131072    (65536)
// sbox     : float4[N]         @ 262144    (262144)
// sarea    : f32[N]            @ 524288    (65536)
// mask     : u64[N*NWORDS]     @ 589824    (33554432)
// idxArr   : i32[32]           @ 34144256  (128)   [30]=ticket/ncand
// keepw    : u64[256]          @ 34144384  (2048)
// validw   : u64[256]          @ 34146432  (2048)
// scoresW  : f32[25*65]        @ 34148480  (6500)
//
// ROUND 11: round 10 hit 231.7 us with every one of our kernels under
// ~43 us (top-5 = harness 285MB ws-poison fills at 83% HBM peak — chip is
// NOT down-clocked). Sum of kernel work ~60-90 us => ~130 us of the total
// is inter-dispatch gap across 8 enqueues. Fuse the entire pipeline into
// ONE cooperative kernel (64 blocks x 256 threads, trivially co-resident);
// 7 grid.sync()s (~2-4 us each) replace 7 dispatch gaps (~10-15 us each).
// All stage bodies are the round-10-proven code; mask stage re-expressed
// per-wave via __shfl (same arithmetic, no intra-stage barriers).

// First-K pick from the valid bitmask: wave 0, lane l owns words l*4..l*4+3.
__device__ __forceinline__ void pick_first_k(
        const unsigned long long* __restrict__ validw,
        int* idxL, int* cntL, int tid) {
    if (tid < K) idxL[tid] = 0;          // fill_value = 0
    __syncthreads();
    if (tid < 64) {
        int lane = tid;
        unsigned long long w0 = validw[lane * 4 + 0];
        unsigned long long w1 = validw[lane * 4 + 1];
        unsigned long long w2 = validw[lane * 4 + 2];
        unsigned long long w3 = validw[lane * 4 + 3];
        int s = (int)(__popcll(w0) + __popcll(w1) + __popcll(w2) + __popcll(w3));
        int pref = s;                                  // inclusive prefix
        for (int off = 1; off < 64; off <<= 1) {
            int v = __shfl_up(pref, off, 64);
            if (lane >= off) pref += v;
        }
        int excl = pref - s;
        int total = __shfl(pref, 63, 64);
        if (lane == 0) *cntL = total;
        if (excl < K) {
            unsigned long long wsv[4] = { w0, w1, w2, w3 };
            int rk = excl;
            for (int q = 0; q < 4; ++q) {
                unsigned long long ww = wsv[q];
                while (ww && rk < K) {
                    int j = __ffsll((long long)ww) - 1;
                    ww &= ww - 1ull;
                    idxL[rk++] = (lane * 4 + q) * 64 + j;
                }
            }
        }
    }
    __syncthreads();
}

__global__ void __launch_bounds__(256, 1)
k_all(const float* __restrict__ roi_boxes,
      const float* __restrict__ roi_scores,
      const float* __restrict__ det_boxes,
      const float* __restrict__ vis,
      const float* __restrict__ info,
      const float* __restrict__ tf,
      unsigned long long* __restrict__ ckeys,
      unsigned int* __restrict__ rank,
      float4* __restrict__ sbox,
      float* __restrict__ sarea,
      unsigned long long* __restrict__ mask,
      int* __restrict__ ticket,
      unsigned long long* __restrict__ keepw_ws,
      unsigned long long* __restrict__ validw,
      float* __restrict__ scoresW,
      float* __restrict__ out) {
    cg::grid_group grid = cg::this_grid();
    int bid = blockIdx.x, tid = threadIdx.x;
    int gi = bid * 256 + tid;            // 0..16383
    int lane = tid & 63;
    int wv = tid >> 6;                   // wave within block, 0..3

    __shared__ unsigned long long lk[2048];          // 16 KB (crank staging)
    __shared__ unsigned long long keepw_arr[NWORDS]; // 2 KB (scan)
    __shared__ int keptList[1024];                   // 4 KB (scan)
    __shared__ float featL[FEAT];                    // 2 KB (gemm)
    __shared__ float scL[K * NUM_CATS];              // 6.5 KB (final)
    __shared__ float keyL[K];
    __shared__ int fgL[K];
    __shared__ int ordL[K];
    __shared__ int idxL[K];
    __shared__ int cntL;

    // ---------------- P0: init ----------------
    if (gi == 0) *ticket = 0;
    grid.sync();

    // ---------------- P1: build (compact candidate keys) ----------------
    {
        float s = roi_scores[gi];
        rank[gi] = 0u;                       // safe default for non-candidates
        bool cand = s >= 0.9f;
        unsigned long long bal = __ballot(cand);
        int base = 0;
        if (lane == 0) base = atomicAdd(ticket, (int)__popcll(bal));
        base = __shfl(base, 0, 64);
        if (cand) {
            int pre = (int)__popcll(bal & ((1ull << lane) - 1ull));
            ckeys[base + pre] =
                ((unsigned long long)__float_as_uint(s) << 32) |
                (unsigned long long)(0xFFFFFFFFu - (unsigned)gi);
        }
    }
    grid.sync();

    int nc = *ticket;
    if (nc < 0) nc = 0;
    if (nc > N) nc = N;
    int NC = (nc + 63) >> 6;

    // ---------------- P2: crank (rank candidates, scatter sorted) ----------
    if (bid * 256 < nc) {                    // uniform per block
        int ci = gi;
        unsigned long long my = (ci < nc) ? ckeys[ci] : 0ull;
        unsigned int cnt = 0;
        for (int j0 = 0; j0 < nc; j0 += 2048) {
            int m = nc - j0; if (m > 2048) m = 2048;
            __syncthreads();
            for (int t2 = tid; t2 < m; t2 += 256) lk[t2] = ckeys[j0 + t2];
            __syncthreads();
            if (ci < nc) {
#pragma unroll 8
                for (int t2 = 0; t2 < m; ++t2) cnt += (lk[t2] > my) ? 1u : 0u;
            }
        }
        if (ci < nc) {
            unsigned int o = 0xFFFFFFFFu - (unsigned int)my;   // original index
            rank[o] = cnt;                                     // global sorted pos
            float4 b = ((const float4*)det_boxes)[o];          // [y1,x1,y2,x2]
            sbox[cnt] = b;
            sarea[cnt] = (b.w - b.y) * (b.z - b.x);            // (x2-x1)*(y2-y1)
        }
    }
    grid.sync();

    // ---------------- P3: mask (per-wave tiles via shfl) ----------------
    {
        int total = NC * (NC + 1) / 2;
        for (int tile = bid * 4 + wv; tile < total; tile += 256) {
            int cb = (int)((sqrtf(8.0f * (float)tile + 1.0f) - 1.0f) * 0.5f);
            while ((cb + 1) * (cb + 2) / 2 <= tile) ++cb;
            while (cb * (cb + 1) / 2 > tile) --cb;
            int rb = tile - cb * (cb + 1) / 2;
            int col0 = cb * 64;
            float4 cbm = sbox[col0 + lane];      // lane holds column box
            float cam = sarea[col0 + lane];
            int row = rb * 64 + lane;
            float4 r = sbox[row];
            float ra = sarea[row];
            unsigned long long bits = 0ull;
            for (int j = 0; j < 64; ++j) {
                float bx = __shfl(cbm.x, j, 64);
                float by = __shfl(cbm.y, j, 64);
                float bz = __shfl(cbm.z, j, 64);
                float bw = __shfl(cbm.w, j, 64);
                float ba = __shfl(cam, j, 64);
                int col = col0 + j;
                if (col > row) {
                    float iw = fminf(r.w, bw) - fmaxf(r.y, by);  // x overlap
                    iw = fmaxf(iw, 0.0f);
                    float ih = fminf(r.z, bz) - fmaxf(r.x, bx);  // y overlap
                    ih = fmaxf(ih, 0.0f);
                    float inter = iw * ih;
                    float iou = inter / (ra + ba - inter + 1e-12f);
                    if (iou > 0.6f) bits |= (1ull << j);
                }
            }
            mask[(size_t)row * NWORDS + cb] = bits;
        }
    }
    grid.sync();

    // ---------------- P4: scan (block 0, wave 0; round-10 proven) ----------
    if (bid == 0 && tid < 64) {
        for (int i2 = lane; i2 < NWORDS; i2 += 64) keepw_arr[i2] = 0ull;

        int cnt = 0, nk = 0;
        unsigned long long dnext = 0ull;
        if (NC > 0) dnext = mask[(size_t)lane * NWORDS];   // chunk 0 diag word

        for (int c = 0; c < NC; ++c) {
            if (cnt >= MAX_DETS) break;

            unsigned long long dcur = dnext;
            if (c + 1 < NC)
                dnext = mask[(size_t)((c + 1) * 64 + lane) * NWORDS + (c + 1)];
            unsigned int dlo = (unsigned int)dcur;
            unsigned int dhi = (unsigned int)(dcur >> 32);

            // lazy suppression gather: supp_c = OR over kept t of mask[t][c]
            unsigned long long acc = 0ull;
            {
                int q = lane;
                while (q < nk) {
#define GS(i)                                                             \
                    unsigned long long G##i = 0ull;                       \
                    {                                                     \
                        int qq = q + 64 * i;                              \
                        if (qq < nk) {                                    \
                            int t = keptList[qq];                         \
                            G##i = mask[(size_t)t * NWORDS + c];          \
                        }                                                 \
                    }
                    GS(0) GS(1) GS(2) GS(3) GS(4) GS(5) GS(6) GS(7)
#undef GS
                    acc |= G0 | G1 | G2 | G3 | G4 | G5 | G6 | G7;
                    q += 512;
                }
            }
            unsigned int alo = (unsigned int)acc;
            unsigned int ahi = (unsigned int)(acc >> 32);
            for (int off = 32; off > 0; off >>= 1) {
                alo |= (unsigned int)__shfl_xor((int)alo, off, 64);
                ahi |= (unsigned int)__shfl_xor((int)ahi, off, 64);
            }
            unsigned long long sw =
                ((unsigned long long)(unsigned int)__builtin_amdgcn_readfirstlane(
                     (int)ahi) << 32) |
                 (unsigned long long)(unsigned int)__builtin_amdgcn_readfirstlane(
                     (int)alo);
            unsigned long long alive = ~sw;
            if (nc - c * 64 < 64)                       // clamp tail chunk
                alive &= ((1ull << (nc - c * 64)) - 1ull);

            unsigned long long zb = __ballot(dcur == 0ull);

            // phase A with zero-row shortcut
            unsigned long long keepw = 0ull;
            unsigned long long NZ = alive & ~zb;
            while (true) {
                unsigned long long below;
                int t = -1;
                if (NZ) { t = __ffsll((long long)NZ) - 1; below = (1ull << t) - 1ull; }
                else below = ~0ull;
                unsigned long long seg = alive & below;
                int segc = (int)__popcll(seg);
                if (cnt + segc >= MAX_DETS) {
                    int allow = MAX_DETS - cnt;
                    unsigned long long r = 0ull;
                    for (int k2 = 0; k2 < allow; ++k2) {
                        unsigned long long b = seg & (~seg + 1ull);
                        r |= b; seg ^= b;
                    }
                    keepw |= r; cnt = MAX_DETS; break;
                }
                keepw |= seg; cnt += segc; alive &= ~seg;
                if (t < 0) break;
                keepw |= (1ull << t); ++cnt;
                if (cnt >= MAX_DETS) break;
                unsigned long long dt =
                    ((unsigned long long)(unsigned int)__builtin_amdgcn_readlane(
                         (int)dhi, t) << 32) |
                     (unsigned long long)(unsigned int)__builtin_amdgcn_readlane(
                         (int)dlo, t);
                alive &= ~(dt | (1ull << t));
                NZ &= alive;
                NZ &= ~(1ull << t);
            }
            if (lane == 0) keepw_arr[c] = keepw;

            if (keepw != 0ull) {
                if ((keepw >> lane) & 1ull) {
                    int pre = (int)__popcll(keepw & ((1ull << lane) - 1ull));
                    keptList[nk + pre] = c * 64 + lane;
                }
                nk += (int)__popcll(keepw);
            }
        }
        for (int i2 = lane; i2 < NWORDS; i2 += 64) keepw_ws[i2] = keepw_arr[i2];
    }
    grid.sync();

    // ---------------- P5: valid bits ----------------
    {
        float sy = info[4], sx = info[5];
        unsigned int r = rank[gi];
        bool keep = ((keepw_ws[(r >> 6) & (NWORDS - 1)] >> (r & 63)) & 1ull) != 0ull;
        float4 rb = ((const float4*)roi_boxes)[gi];
        bool nz = !((rb.x == 0.0f) && (rb.y == 0.0f) && (rb.z == 0.0f) && (rb.w == 0.0f));
        bool sc = roi_scores[gi] >= 0.9f;
        float4 db = ((const float4*)det_boxes)[gi];
        float r0 = db.x / sy, r1 = db.y / sx, r2 = db.z / sy, r3 = db.w / sx;
        bool big = ((r2 - r0) * (r3 - r1)) > 220.0f;
        bool valid = keep && nz && sc && big;
        unsigned long long bal = __ballot(valid);
        if (lane == 0) validw[gi >> 6] = bal;
    }
    grid.sync();

    // ---------------- P6: gemm (blocks 0..24) ----------------
    if (bid < K) {
        pick_first_k(validw, idxL, &cntL, tid);
        int o = idxL[bid];
        if (tid < 128)
            ((float4*)featL)[tid] = ((const float4*)(vis + (size_t)o * FEAT))[tid];
        __syncthreads();
        if (tid < NUM_CATS) {
            const float* tr = &tf[(size_t)tid * FEAT];
            float s = 0.0f;
#pragma unroll 8
            for (int e = 0; e < FEAT; ++e) s += featL[e] * tr[e];
            scoresW[bid * NUM_CATS + tid] = s;
        }
    }
    grid.sync();

    // ---------------- P7: final (block 0) ----------------
    if (bid == 0) {
        pick_first_k(validw, idxL, &cntL, tid);

        for (int p = tid; p < K * NUM_CATS; p += 256) scL[p] = scoresW[p];
        __syncthreads();

        int count = cntL;
        int mincount = count < K ? count : K;

        if (tid < K) {
            float mv = scL[tid * NUM_CATS];
            int ma = 0;
            for (int c = 1; c < NUM_CATS; ++c) {
                float v = scL[tid * NUM_CATS + c];
                if (v > mv) { mv = v; ma = c; }     // first-max (jnp.argmax)
            }
            int fg = (tid < mincount) && (ma != 0);
            fgL[tid] = fg;
            keyL[tid] = fg ? mv : -INFINITY;
        }
        __syncthreads();

        if (tid == 0) {                 // stable selection sort, descending
            unsigned used = 0;
            for (int p = 0; p < K; ++p) {
                int bk = -1; float bv = 0.0f;
                for (int k2 = 0; k2 < K; ++k2) {
                    if (used & (1u << k2)) continue;
                    if (bk < 0 || keyL[k2] > bv) { bk = k2; bv = keyL[k2]; }
                }
                ordL[p] = bk;
                used |= (1u << bk);
            }
        }
        __syncthreads();

        float sy = info[4], sx = info[5];
        // scores: [0 .. 1599]
        for (int p = tid; p < K * (NUM_CATS - 1); p += 256) {
            int q = p >> 6, cc = p & 63;
            int src = ordL[q];
            out[p] = fgL[src] ? scL[src * NUM_CATS + cc + 1] : 0.0f;
        }
        // bboxes: [1600 .. 1699]  processed = [xmin, ymin, xmax, ymax]
        for (int p = tid; p < K * 4; p += 256) {
            int q = p >> 2, e = p & 3;
            int src = ordL[q];
            float v = 0.0f;
            if (fgL[src]) {
                int o = idxL[src];
                float b0 = det_boxes[o * 4 + 0] / sy;   // ymin
                float b1 = det_boxes[o * 4 + 1] / sx;   // xmin
                float b2 = det_boxes[o * 4 + 2] / sy;   // ymax
                float b3 = det_boxes[o * 4 + 3] / sx;   // xmax
                v = (e == 0) ? b1 : (e == 1) ? b0 : (e == 2) ? b3 : b2;
            }
            out[1600 + p] = v;
        }
        // mask: [1700 .. 1724]
        if (tid < K) out[1700 + tid] = fgL[ordL[tid]] ? 1.0f : 0.0f;
    }
}

extern "C" void kernel_launch(void* const* d_in, const int* in_sizes, int n_in,
                              void* d_out, int out_size, void* d_ws, size_t ws_size,
                              hipStream_t stream) {
    const float* roi_boxes  = (const float*)d_in[0];
    const float* roi_scores = (const float*)d_in[1];
    const float* det_boxes  = (const float*)d_in[2];
    // d_in[3] detection_masks: unused by reference
    const float* vis        = (const float*)d_in[4];
    const float* info       = (const float*)d_in[5];
    const float* tf         = (const float*)d_in[6];

    char* ws = (char*)d_ws;
    unsigned long long* ckeys  = (unsigned long long*)(ws + 0);
    unsigned int* rankp        = (unsigned int*)(ws + 131072);
    float4* sboxp              = (float4*)(ws + 262144);
    float* sareap              = (float*)(ws + 524288);
    unsigned long long* maskp  = (unsigned long long*)(ws + 589824);
    int* idxArr                = (int*)(ws + 34144256);
    unsigned long long* keepw  = (unsigned long long*)(ws + 34144384);
    unsigned long long* validw = (unsigned long long*)(ws + 34146432);
    float* scoresW             = (float*)(ws + 34148480);
    int* ticket                = idxArr + 30;
    float* outp                = (float*)d_out;

    void* args[] = {
        (void*)&roi_boxes, (void*)&roi_scores, (void*)&det_boxes,
        (void*)&vis, (void*)&info, (void*)&tf,
        (void*)&ckeys, (void*)&rankp, (void*)&sboxp, (void*)&sareap,
        (void*)&maskp, (void*)&ticket, (void*)&keepw, (void*)&validw,
        (void*)&scoresW, (void*)&outp
    };
    hipLaunchCooperativeKernel((const void*)k_all, dim3(64), dim3(256),
                               args, 0, stream);
}